// Round 1
// baseline (844.885 us; speedup 1.0000x reference)
//
#include <hip/hip_runtime.h>
#include <hip/hip_bf16.h>

#define NMAX 20
#define NPAIR (NMAX * (NMAX - 1) / 2)   // 190
#define TPB1 256
#define TPB2 256
#define MAXBLK 2048

// Monotone map f32 -> u32 (order-preserving), packed with ~index so that
// u64 max == (max value, tie -> lowest index). Matches jax top_k tie rule.
__device__ __forceinline__ unsigned long long packKey(float v, unsigned i) {
    unsigned u = __float_as_uint(v);
    u = (u & 0x80000000u) ? ~u : (u | 0x80000000u);
    return ((unsigned long long)u << 32) | (unsigned long long)(~i);
}

// ---------------- Kernel 1: per-block partial sums of |t - p| ----------------
__global__ void __launch_bounds__(TPB1)
l1_partial_kernel(const float4* __restrict__ t, const float4* __restrict__ p,
                  float* __restrict__ partial, int nvec) {
    float s = 0.f;
    int stride = gridDim.x * blockDim.x;
    for (int i = blockIdx.x * blockDim.x + threadIdx.x; i < nvec; i += stride) {
        float4 a = t[i];
        float4 b = p[i];
        s += fabsf(a.x - b.x) + fabsf(a.y - b.y) +
             fabsf(a.z - b.z) + fabsf(a.w - b.w);
    }
    // wave-64 shuffle reduce
    #pragma unroll
    for (int o = 32; o > 0; o >>= 1) s += __shfl_down(s, o, 64);
    __shared__ float wsum[TPB1 / 64];
    int lane = threadIdx.x & 63;
    int wid  = threadIdx.x >> 6;
    if (lane == 0) wsum[wid] = s;
    __syncthreads();
    if (threadIdx.x == 0) {
        float tot = 0.f;
        #pragma unroll
        for (int w = 0; w < TPB1 / 64; ++w) tot += wsum[w];
        partial[blockIdx.x] = tot;
    }
}

// ---------------- Kernel 2: finalize (l1 reduce + top-k + pdist std) ----------
__global__ void __launch_bounds__(TPB2)
finalize_kernel(const float* __restrict__ partials, int nPartials,
                const float* __restrict__ latent, int nLat,
                const float* __restrict__ R_xyz, int G,
                float* __restrict__ out, float invN) {
    __shared__ float red[TPB2];
    __shared__ unsigned long long cand[TPB2 * NMAX];  // 40 KB
    __shared__ unsigned long long redk[TPB2];
    __shared__ int   sel[NMAX];
    __shared__ float sxyz[NMAX][3];
    __shared__ float s_l1, s_sum;

    int tid = threadIdx.x;

    // ---- Phase 1: reduce L1 partials (deterministic order) ----
    {
        float s = 0.f;
        for (int i = tid; i < nPartials; i += TPB2) s += partials[i];
        red[tid] = s;
        __syncthreads();
        for (int off = TPB2 / 2; off > 0; off >>= 1) {
            if (tid < off) red[tid] += red[tid + off];
            __syncthreads();
        }
        if (tid == 0) s_l1 = red[0] * invN;
        __syncthreads();
    }

    // ---- Phase 2: per-thread local top-20 of latent (packed keys) ----
    {
        unsigned long long loc[NMAX];
        #pragma unroll
        for (int k = 0; k < NMAX; ++k) loc[k] = 0ull;
        for (int i = tid; i < nLat; i += TPB2) {
            unsigned long long key = packKey(latent[i], (unsigned)i);
            if (key > loc[NMAX - 1]) {
                int p = NMAX - 1;
                while (p > 0 && key > loc[p - 1]) { loc[p] = loc[p - 1]; --p; }
                loc[p] = key;
            }
        }
        #pragma unroll
        for (int k = 0; k < NMAX; ++k) cand[tid * NMAX + k] = loc[k];
        __syncthreads();
    }

    // ---- Phase 3: 20 rounds of block argmax with key < prev exclusion ----
    {
        unsigned long long prev = 0xFFFFFFFFFFFFFFFFull;
        for (int r = 0; r < NMAX; ++r) {
            unsigned long long m = 0ull;
            #pragma unroll
            for (int k = 0; k < NMAX; ++k) {
                unsigned long long c = cand[tid * NMAX + k];
                if (c < prev && c > m) m = c;
            }
            redk[tid] = m;
            __syncthreads();
            for (int off = TPB2 / 2; off > 0; off >>= 1) {
                if (tid < off && redk[tid + off] > redk[tid]) redk[tid] = redk[tid + off];
                __syncthreads();
            }
            if (tid == 0) sel[r] = (int)(~(unsigned)redk[0]);
            __syncthreads();
            prev = redk[0];
            __syncthreads();
        }
    }

    // ---- Phase 4: gather xyz of selected points ----
    if (tid < NMAX * 3) {
        int i = tid / 3, d = tid % 3;
        sxyz[i][d] = R_xyz[d * G + sel[i]];
    }
    __syncthreads();

    // ---- Phase 5: 190 pairwise distances, std (ddof=1) ----
    float dval = 0.f;
    if (tid < NPAIR) {
        int k = tid, i = 0, rem = NMAX - 1;
        while (k >= rem) { k -= rem; ++i; --rem; }
        int j = i + 1 + k;
        float dx = sxyz[i][0] - sxyz[j][0];
        float dy = sxyz[i][1] - sxyz[j][1];
        float dz = sxyz[i][2] - sxyz[j][2];
        dval = sqrtf(dx * dx + dy * dy + dz * dz);
    }
    red[tid] = dval;
    __syncthreads();
    for (int off = TPB2 / 2; off > 0; off >>= 1) {
        if (tid < off) red[tid] += red[tid + off];
        __syncthreads();
    }
    if (tid == 0) s_sum = red[0];
    __syncthreads();
    red[tid] = dval * dval;
    __syncthreads();
    for (int off = TPB2 / 2; off > 0; off >>= 1) {
        if (tid < off) red[tid] += red[tid + off];
        __syncthreads();
    }
    if (tid == 0) {
        float sum   = s_sum;
        float sumsq = red[0];
        float mean  = sum / (float)NPAIR;
        float var   = (sumsq - (float)NPAIR * mean * mean) / (float)(NPAIR - 1);
        float stdv  = sqrtf(fmaxf(var, 0.f));
        float reg   = 0.01f * stdv;
        out[0] = s_l1 + reg;
        out[1] = s_l1;
        out[2] = reg;
    }
}

extern "C" void kernel_launch(void* const* d_in, const int* in_sizes, int n_in,
                              void* d_out, int out_size, void* d_ws, size_t ws_size,
                              hipStream_t stream) {
    const float* target = (const float*)d_in[0];
    const float* pred   = (const float*)d_in[1];
    const float* latent = (const float*)d_in[2];
    const float* R_xyz  = (const float*)d_in[3];
    float* out = (float*)d_out;

    int n     = in_sizes[0];          // 33,554,432
    int nLat  = in_sizes[2];          // 64,800
    int G     = in_sizes[3] / 3;      // 64,800
    int nvec  = n / 4;                // n divisible by 4

    int blocks = (nvec + TPB1 - 1) / TPB1;
    if (blocks > MAXBLK) blocks = MAXBLK;

    float* partials = (float*)d_ws;   // blocks floats

    l1_partial_kernel<<<blocks, TPB1, 0, stream>>>(
        (const float4*)target, (const float4*)pred, partials, nvec);

    finalize_kernel<<<1, TPB2, 0, stream>>>(
        partials, blocks, latent, nLat, R_xyz, G, out, 1.0f / (float)n);
}

// Round 2
// 72.692 us; speedup vs baseline: 11.6227x; 11.6227x over previous
//
#include <hip/hip_runtime.h>
#include <hip/hip_bf16.h>

#define NMAX 20
#define NPAIR (NMAX * (NMAX - 1) / 2)   // 190
#define TPB 256
#define L1_BLOCKS 2048
#define TOPK_BLOCKS 16

// Monotone map f32 -> u32 (order-preserving), packed with ~index so that
// u64 max == (max value, tie -> lowest index). Matches jax top_k tie rule.
__device__ __forceinline__ unsigned long long packKey(float v, unsigned i) {
    unsigned u = __float_as_uint(v);
    u = (u & 0x80000000u) ? ~u : (u | 0x80000000u);
    return ((unsigned long long)u << 32) | (unsigned long long)(~i);
}

// ------------- Kernel 1 (fused): topk blocks [0,16) + L1 blocks [16, 16+2048) -
__global__ void __launch_bounds__(TPB)
fused_kernel(const float4* __restrict__ t, const float4* __restrict__ p, int nvec,
             const float* __restrict__ latent, int nLat,
             float* __restrict__ partial, unsigned long long* __restrict__ keysOut) {
    if (blockIdx.x >= TOPK_BLOCKS) {
        // ---------------- L1 partial sums of |t - p| ----------------
        int bid = blockIdx.x - TOPK_BLOCKS;
        float s = 0.f;
        int stride = L1_BLOCKS * TPB;
        for (int i = bid * TPB + threadIdx.x; i < nvec; i += stride) {
            float4 a = t[i];
            float4 b = p[i];
            s += fabsf(a.x - b.x) + fabsf(a.y - b.y) +
                 fabsf(a.z - b.z) + fabsf(a.w - b.w);
        }
        #pragma unroll
        for (int o = 32; o > 0; o >>= 1) s += __shfl_down(s, o, 64);
        __shared__ float wsum[TPB / 64];
        int lane = threadIdx.x & 63;
        int wid  = threadIdx.x >> 6;
        if (lane == 0) wsum[wid] = s;
        __syncthreads();
        if (threadIdx.x == 0) {
            float tot = 0.f;
            #pragma unroll
            for (int w = 0; w < TPB / 64; ++w) tot += wsum[w];
            partial[bid] = tot;
        }
    } else {
        // ---------------- top-k partial: block-top-20 of a strided subset ----
        int b   = blockIdx.x;          // 0..15
        int tid = threadIdx.x;
        int lane = tid & 63, wid = tid >> 6;

        // Per-thread top-20 in REGISTERS (sentinel 0 < any real key).
        // <=16 elements per thread, so the local list holds everything seen.
        unsigned long long loc[NMAX];
        #pragma unroll
        for (int k = 0; k < NMAX; ++k) loc[k] = 0ull;

        for (int i = b * TPB + tid; i < nLat; i += TOPK_BLOCKS * TPB) {
            unsigned long long key = packKey(latent[i], (unsigned)i);
            // Branch-free sorted insert, STATIC indices only (stays in VGPRs).
            // Iterate high->low so each step reads original loc[k-1], loc[k].
            #pragma unroll
            for (int k = NMAX - 1; k >= 1; --k) {
                loc[k] = (key > loc[k - 1]) ? loc[k - 1]
                                            : ((key > loc[k]) ? key : loc[k]);
            }
            loc[0] = (key > loc[0]) ? key : loc[0];
        }

        // Block-level: 20 rounds of argmax with "key < prev" exclusion.
        __shared__ unsigned long long wmax[TPB / 64];
        __shared__ unsigned long long selk;
        unsigned long long prev = ~0ull;
        for (int r = 0; r < NMAX; ++r) {
            unsigned long long m = 0ull;
            #pragma unroll
            for (int k = 0; k < NMAX; ++k) {
                unsigned long long c = loc[k];
                m = (c < prev && c > m) ? c : m;
            }
            #pragma unroll
            for (int o = 32; o > 0; o >>= 1) {
                unsigned long long other = __shfl_down(m, o, 64);
                if (other > m) m = other;
            }
            if (lane == 0) wmax[wid] = m;
            __syncthreads();
            if (tid == 0) {
                unsigned long long mm = wmax[0];
                #pragma unroll
                for (int w = 1; w < TPB / 64; ++w) if (wmax[w] > mm) mm = wmax[w];
                selk = mm;
                keysOut[b * NMAX + r] = mm;
            }
            __syncthreads();
            prev = selk;
        }
    }
}

// ---------------- Kernel 2: finalize (merge + pdist std + combine) ------------
__global__ void __launch_bounds__(TPB)
finalize_kernel(const float* __restrict__ partials, int nPartials,
                const unsigned long long* __restrict__ keys,  // TOPK_BLOCKS*NMAX
                const float* __restrict__ R_xyz, int G,
                float* __restrict__ out, float invN) {
    __shared__ float red[TPB];
    __shared__ unsigned long long ck[TOPK_BLOCKS * NMAX];   // 320 keys
    __shared__ unsigned long long wmax[TPB / 64];
    __shared__ unsigned long long selk;
    __shared__ int   sel[NMAX];
    __shared__ float sxyz[NMAX][3];
    __shared__ float s_l1, s_sum;

    int tid = threadIdx.x, lane = tid & 63, wid = tid >> 6;

    // ---- Phase 1: reduce L1 partials (deterministic order) ----
    {
        float s = 0.f;
        for (int i = tid; i < nPartials; i += TPB) s += partials[i];
        red[tid] = s;
        __syncthreads();
        for (int off = TPB / 2; off > 0; off >>= 1) {
            if (tid < off) red[tid] += red[tid + off];
            __syncthreads();
        }
        if (tid == 0) s_l1 = red[0] * invN;
        __syncthreads();
    }

    // ---- Phase 2: merge the 16 block-top-20 lists -> global top-20 ----
    for (int i = tid; i < TOPK_BLOCKS * NMAX; i += TPB) ck[i] = keys[i];
    __syncthreads();
    {
        unsigned long long prev = ~0ull;
        for (int r = 0; r < NMAX; ++r) {
            unsigned long long m = 0ull;
            for (int i = tid; i < TOPK_BLOCKS * NMAX; i += TPB) {
                unsigned long long c = ck[i];
                m = (c < prev && c > m) ? c : m;
            }
            #pragma unroll
            for (int o = 32; o > 0; o >>= 1) {
                unsigned long long other = __shfl_down(m, o, 64);
                if (other > m) m = other;
            }
            if (lane == 0) wmax[wid] = m;
            __syncthreads();
            if (tid == 0) {
                unsigned long long mm = wmax[0];
                #pragma unroll
                for (int w = 1; w < TPB / 64; ++w) if (wmax[w] > mm) mm = wmax[w];
                selk = mm;
                sel[r] = (int)(~(unsigned)mm);
            }
            __syncthreads();
            prev = selk;
        }
    }

    // ---- Phase 3: gather xyz of selected points ----
    if (tid < NMAX * 3) {
        int i = tid / 3, d = tid % 3;
        sxyz[i][d] = R_xyz[d * G + sel[i]];
    }
    __syncthreads();

    // ---- Phase 4: 190 pairwise distances, std (ddof=1) ----
    float dval = 0.f;
    if (tid < NPAIR) {
        int k = tid, i = 0, rem = NMAX - 1;
        while (k >= rem) { k -= rem; ++i; --rem; }
        int j = i + 1 + k;
        float dx = sxyz[i][0] - sxyz[j][0];
        float dy = sxyz[i][1] - sxyz[j][1];
        float dz = sxyz[i][2] - sxyz[j][2];
        dval = sqrtf(dx * dx + dy * dy + dz * dz);
    }
    red[tid] = dval;
    __syncthreads();
    for (int off = TPB / 2; off > 0; off >>= 1) {
        if (tid < off) red[tid] += red[tid + off];
        __syncthreads();
    }
    if (tid == 0) s_sum = red[0];
    __syncthreads();
    red[tid] = dval * dval;
    __syncthreads();
    for (int off = TPB / 2; off > 0; off >>= 1) {
        if (tid < off) red[tid] += red[tid + off];
        __syncthreads();
    }
    if (tid == 0) {
        float sum   = s_sum;
        float sumsq = red[0];
        float mean  = sum / (float)NPAIR;
        float var   = (sumsq - (float)NPAIR * mean * mean) / (float)(NPAIR - 1);
        float stdv  = sqrtf(fmaxf(var, 0.f));
        float reg   = 0.01f * stdv;
        out[0] = s_l1 + reg;
        out[1] = s_l1;
        out[2] = reg;
    }
}

extern "C" void kernel_launch(void* const* d_in, const int* in_sizes, int n_in,
                              void* d_out, int out_size, void* d_ws, size_t ws_size,
                              hipStream_t stream) {
    const float* target = (const float*)d_in[0];
    const float* pred   = (const float*)d_in[1];
    const float* latent = (const float*)d_in[2];
    const float* R_xyz  = (const float*)d_in[3];
    float* out = (float*)d_out;

    int n    = in_sizes[0];          // 33,554,432
    int nLat = in_sizes[2];          // 64,800
    int G    = in_sizes[3] / 3;      // 64,800
    int nvec = n / 4;

    // ws layout: [0, 2048) floats = L1 partials; at byte 8192: 16*20 u64 keys.
    float* partials = (float*)d_ws;
    unsigned long long* keys = (unsigned long long*)((char*)d_ws + L1_BLOCKS * sizeof(float));

    fused_kernel<<<TOPK_BLOCKS + L1_BLOCKS, TPB, 0, stream>>>(
        (const float4*)target, (const float4*)pred, nvec,
        latent, nLat, partials, keys);

    finalize_kernel<<<1, TPB, 0, stream>>>(
        partials, L1_BLOCKS, keys, R_xyz, G, out, 1.0f / (float)n);
}

// Round 3
// 72.180 us; speedup vs baseline: 11.7052x; 1.0071x over previous
//
#include <hip/hip_runtime.h>
#include <hip/hip_bf16.h>

#define NMAX 20
#define NPAIR (NMAX * (NMAX - 1) / 2)   // 190
#define TPB 256
#define L1_BLOCKS 2048
#define TOPK_BLOCKS 16

// Monotone map f32 -> u32 (order-preserving), packed with ~index so that
// u64 max == (max value, tie -> lowest index). Matches jax top_k tie rule.
__device__ __forceinline__ unsigned long long packKey(float v, unsigned i) {
    unsigned u = __float_as_uint(v);
    u = (u & 0x80000000u) ? ~u : (u | 0x80000000u);
    return ((unsigned long long)u << 32) | (unsigned long long)(~i);
}

__device__ __forceinline__ float absdiff4(float4 a, float4 b) {
    return fabsf(a.x - b.x) + fabsf(a.y - b.y) +
           fabsf(a.z - b.z) + fabsf(a.w - b.w);
}

// ------------- Kernel 1 (fused): topk blocks [0,16) + L1 blocks [16, 16+2048) -
__global__ void __launch_bounds__(TPB)
fused_kernel(const float4* __restrict__ t, const float4* __restrict__ p, int nvec,
             const float* __restrict__ latent, int nLat,
             float* __restrict__ partial, unsigned long long* __restrict__ keysOut) {
    if (blockIdx.x >= TOPK_BLOCKS) {
        // ---------------- L1 partial sums of |t - p| ----------------
        int bid = blockIdx.x - TOPK_BLOCKS;
        int stride = L1_BLOCKS * TPB;
        int i = bid * TPB + threadIdx.x;

        float s0 = 0.f, s1 = 0.f, s2 = 0.f, s3 = 0.f;
        // Main: 4x unrolled, 8 independent 16B loads in flight per trip.
        for (; i + 3 * stride < nvec; i += 4 * stride) {
            float4 a0 = t[i];
            float4 a1 = t[i + stride];
            float4 a2 = t[i + 2 * stride];
            float4 a3 = t[i + 3 * stride];
            float4 b0 = p[i];
            float4 b1 = p[i + stride];
            float4 b2 = p[i + 2 * stride];
            float4 b3 = p[i + 3 * stride];
            s0 += absdiff4(a0, b0);
            s1 += absdiff4(a1, b1);
            s2 += absdiff4(a2, b2);
            s3 += absdiff4(a3, b3);
        }
        // Tail
        for (; i < nvec; i += stride) {
            s0 += absdiff4(t[i], p[i]);
        }
        float s = (s0 + s1) + (s2 + s3);

        #pragma unroll
        for (int o = 32; o > 0; o >>= 1) s += __shfl_down(s, o, 64);
        __shared__ float wsum[TPB / 64];
        int lane = threadIdx.x & 63;
        int wid  = threadIdx.x >> 6;
        if (lane == 0) wsum[wid] = s;
        __syncthreads();
        if (threadIdx.x == 0) {
            float tot = 0.f;
            #pragma unroll
            for (int w = 0; w < TPB / 64; ++w) tot += wsum[w];
            partial[bid] = tot;
        }
    } else {
        // ---------------- top-k partial: block-top-20 of a strided subset ----
        int b   = blockIdx.x;          // 0..15
        int tid = threadIdx.x;
        int lane = tid & 63, wid = tid >> 6;

        // Per-thread top-20 in REGISTERS (sentinel 0 < any real key).
        unsigned long long loc[NMAX];
        #pragma unroll
        for (int k = 0; k < NMAX; ++k) loc[k] = 0ull;

        for (int i = b * TPB + tid; i < nLat; i += TOPK_BLOCKS * TPB) {
            unsigned long long key = packKey(latent[i], (unsigned)i);
            // Branch-free sorted insert, STATIC indices only (stays in VGPRs).
            #pragma unroll
            for (int k = NMAX - 1; k >= 1; --k) {
                loc[k] = (key > loc[k - 1]) ? loc[k - 1]
                                            : ((key > loc[k]) ? key : loc[k]);
            }
            loc[0] = (key > loc[0]) ? key : loc[0];
        }

        // Block-level: 20 rounds of argmax with "key < prev" exclusion.
        __shared__ unsigned long long wmax[TPB / 64];
        __shared__ unsigned long long selk;
        unsigned long long prev = ~0ull;
        for (int r = 0; r < NMAX; ++r) {
            unsigned long long m = 0ull;
            #pragma unroll
            for (int k = 0; k < NMAX; ++k) {
                unsigned long long c = loc[k];
                m = (c < prev && c > m) ? c : m;
            }
            #pragma unroll
            for (int o = 32; o > 0; o >>= 1) {
                unsigned long long other = __shfl_down(m, o, 64);
                if (other > m) m = other;
            }
            if (lane == 0) wmax[wid] = m;
            __syncthreads();
            if (tid == 0) {
                unsigned long long mm = wmax[0];
                #pragma unroll
                for (int w = 1; w < TPB / 64; ++w) if (wmax[w] > mm) mm = wmax[w];
                selk = mm;
                keysOut[b * NMAX + r] = mm;
            }
            __syncthreads();
            prev = selk;
        }
    }
}

// ---------------- Kernel 2: finalize (merge + pdist std + combine) ------------
__global__ void __launch_bounds__(TPB)
finalize_kernel(const float* __restrict__ partials, int nPartials,
                const unsigned long long* __restrict__ keys,  // TOPK_BLOCKS*NMAX
                const float* __restrict__ R_xyz, int G,
                float* __restrict__ out, float invN) {
    __shared__ float red[TPB];
    __shared__ unsigned long long ck[TOPK_BLOCKS * NMAX];   // 320 keys
    __shared__ unsigned long long wmax[TPB / 64];
    __shared__ unsigned long long selk;
    __shared__ int   sel[NMAX];
    __shared__ float sxyz[NMAX][3];
    __shared__ float s_l1, s_sum;

    int tid = threadIdx.x, lane = tid & 63, wid = tid >> 6;

    // ---- Phase 1: reduce L1 partials (deterministic order) ----
    {
        float s = 0.f;
        for (int i = tid; i < nPartials; i += TPB) s += partials[i];
        red[tid] = s;
        __syncthreads();
        for (int off = TPB / 2; off > 0; off >>= 1) {
            if (tid < off) red[tid] += red[tid + off];
            __syncthreads();
        }
        if (tid == 0) s_l1 = red[0] * invN;
        __syncthreads();
    }

    // ---- Phase 2: merge the 16 block-top-20 lists -> global top-20 ----
    for (int i = tid; i < TOPK_BLOCKS * NMAX; i += TPB) ck[i] = keys[i];
    __syncthreads();
    {
        unsigned long long prev = ~0ull;
        for (int r = 0; r < NMAX; ++r) {
            unsigned long long m = 0ull;
            for (int i = tid; i < TOPK_BLOCKS * NMAX; i += TPB) {
                unsigned long long c = ck[i];
                m = (c < prev && c > m) ? c : m;
            }
            #pragma unroll
            for (int o = 32; o > 0; o >>= 1) {
                unsigned long long other = __shfl_down(m, o, 64);
                if (other > m) m = other;
            }
            if (lane == 0) wmax[wid] = m;
            __syncthreads();
            if (tid == 0) {
                unsigned long long mm = wmax[0];
                #pragma unroll
                for (int w = 1; w < TPB / 64; ++w) if (wmax[w] > mm) mm = wmax[w];
                selk = mm;
                sel[r] = (int)(~(unsigned)mm);
            }
            __syncthreads();
            prev = selk;
        }
    }

    // ---- Phase 3: gather xyz of selected points ----
    if (tid < NMAX * 3) {
        int i = tid / 3, d = tid % 3;
        sxyz[i][d] = R_xyz[d * G + sel[i]];
    }
    __syncthreads();

    // ---- Phase 4: 190 pairwise distances, std (ddof=1) ----
    float dval = 0.f;
    if (tid < NPAIR) {
        int k = tid, i = 0, rem = NMAX - 1;
        while (k >= rem) { k -= rem; ++i; --rem; }
        int j = i + 1 + k;
        float dx = sxyz[i][0] - sxyz[j][0];
        float dy = sxyz[i][1] - sxyz[j][1];
        float dz = sxyz[i][2] - sxyz[j][2];
        dval = sqrtf(dx * dx + dy * dy + dz * dz);
    }
    red[tid] = dval;
    __syncthreads();
    for (int off = TPB / 2; off > 0; off >>= 1) {
        if (tid < off) red[tid] += red[tid + off];
        __syncthreads();
    }
    if (tid == 0) s_sum = red[0];
    __syncthreads();
    red[tid] = dval * dval;
    __syncthreads();
    for (int off = TPB / 2; off > 0; off >>= 1) {
        if (tid < off) red[tid] += red[tid + off];
        __syncthreads();
    }
    if (tid == 0) {
        float sum   = s_sum;
        float sumsq = red[0];
        float mean  = sum / (float)NPAIR;
        float var   = (sumsq - (float)NPAIR * mean * mean) / (float)(NPAIR - 1);
        float stdv  = sqrtf(fmaxf(var, 0.f));
        float reg   = 0.01f * stdv;
        out[0] = s_l1 + reg;
        out[1] = s_l1;
        out[2] = reg;
    }
}

extern "C" void kernel_launch(void* const* d_in, const int* in_sizes, int n_in,
                              void* d_out, int out_size, void* d_ws, size_t ws_size,
                              hipStream_t stream) {
    const float* target = (const float*)d_in[0];
    const float* pred   = (const float*)d_in[1];
    const float* latent = (const float*)d_in[2];
    const float* R_xyz  = (const float*)d_in[3];
    float* out = (float*)d_out;

    int n    = in_sizes[0];          // 33,554,432
    int nLat = in_sizes[2];          // 64,800
    int G    = in_sizes[3] / 3;      // 64,800
    int nvec = n / 4;

    // ws layout: [0, 2048) floats = L1 partials; then 16*20 u64 keys.
    float* partials = (float*)d_ws;
    unsigned long long* keys = (unsigned long long*)((char*)d_ws + L1_BLOCKS * sizeof(float));

    fused_kernel<<<TOPK_BLOCKS + L1_BLOCKS, TPB, 0, stream>>>(
        (const float4*)target, (const float4*)pred, nvec,
        latent, nLat, partials, keys);

    finalize_kernel<<<1, TPB, 0, stream>>>(
        partials, L1_BLOCKS, keys, R_xyz, G, out, 1.0f / (float)n);
}

// Round 4
// 71.466 us; speedup vs baseline: 11.8222x; 1.0100x over previous
//
#include <hip/hip_runtime.h>
#include <hip/hip_bf16.h>

#define NMAX 20
#define NPAIR (NMAX * (NMAX - 1) / 2)   // 190
#define TPB 256
#define L1_BLOCKS 2048
#define TOPK_BLOCKS 16
#define UNROLL 8

// Monotone map f32 -> u32 (order-preserving), packed with ~index so that
// u64 max == (max value, tie -> lowest index). Matches jax top_k tie rule.
__device__ __forceinline__ unsigned long long packKey(float v, unsigned i) {
    unsigned u = __float_as_uint(v);
    u = (u & 0x80000000u) ? ~u : (u | 0x80000000u);
    return ((unsigned long long)u << 32) | (unsigned long long)(~i);
}

__device__ __forceinline__ float absdiff4(float4 a, float4 b) {
    return fabsf(a.x - b.x) + fabsf(a.y - b.y) +
           fabsf(a.z - b.z) + fabsf(a.w - b.w);
}

// ------------- Kernel 1 (fused): topk blocks [0,16) + L1 blocks [16, 16+2048) -
// launch_bounds(256, 4): 4 waves/EU -> VGPR budget 128, lets the allocator
// keep 16 float4 loads in flight (MLP) instead of serializing at 32 VGPRs.
__global__ void __launch_bounds__(TPB, 4)
fused_kernel(const float4* __restrict__ t, const float4* __restrict__ p, int nvec,
             const float* __restrict__ latent, int nLat,
             float* __restrict__ partial, unsigned long long* __restrict__ keysOut) {
    if (blockIdx.x >= TOPK_BLOCKS) {
        // ---------------- L1 partial sums of |t - p| ----------------
        int bid = blockIdx.x - TOPK_BLOCKS;
        int stride = L1_BLOCKS * TPB;
        int i = bid * TPB + threadIdx.x;

        float acc[UNROLL];
        #pragma unroll
        for (int k = 0; k < UNROLL; ++k) acc[k] = 0.f;

        // Main: issue ALL 2*UNROLL independent 16B loads, then consume.
        // Static indices only -> arrays live in VGPRs (no scratch).
        while (i + (UNROLL - 1) * stride < nvec) {
            float4 a[UNROLL], b[UNROLL];
            #pragma unroll
            for (int k = 0; k < UNROLL; ++k) a[k] = t[i + k * stride];
            #pragma unroll
            for (int k = 0; k < UNROLL; ++k) b[k] = p[i + k * stride];
            #pragma unroll
            for (int k = 0; k < UNROLL; ++k) acc[k] += absdiff4(a[k], b[k]);
            i += UNROLL * stride;
        }
        // Tail (not taken for the 32x512x2048 shape: nvec == 16*stride)
        for (; i < nvec; i += stride) acc[0] += absdiff4(t[i], p[i]);

        float s = 0.f;
        #pragma unroll
        for (int k = 0; k < UNROLL; ++k) s += acc[k];

        #pragma unroll
        for (int o = 32; o > 0; o >>= 1) s += __shfl_down(s, o, 64);
        __shared__ float wsum[TPB / 64];
        int lane = threadIdx.x & 63;
        int wid  = threadIdx.x >> 6;
        if (lane == 0) wsum[wid] = s;
        __syncthreads();
        if (threadIdx.x == 0) {
            float tot = 0.f;
            #pragma unroll
            for (int w = 0; w < TPB / 64; ++w) tot += wsum[w];
            partial[bid] = tot;
        }
    } else {
        // ---------------- top-k partial: block-top-20 of a strided subset ----
        int b   = blockIdx.x;          // 0..15
        int tid = threadIdx.x;
        int lane = tid & 63, wid = tid >> 6;

        // Per-thread top-20 in REGISTERS (sentinel 0 < any real key).
        unsigned long long loc[NMAX];
        #pragma unroll
        for (int k = 0; k < NMAX; ++k) loc[k] = 0ull;

        for (int i = b * TPB + tid; i < nLat; i += TOPK_BLOCKS * TPB) {
            unsigned long long key = packKey(latent[i], (unsigned)i);
            // Branch-free sorted insert, STATIC indices only (stays in VGPRs).
            #pragma unroll
            for (int k = NMAX - 1; k >= 1; --k) {
                loc[k] = (key > loc[k - 1]) ? loc[k - 1]
                                            : ((key > loc[k]) ? key : loc[k]);
            }
            loc[0] = (key > loc[0]) ? key : loc[0];
        }

        // Block-level: 20 rounds of argmax with "key < prev" exclusion.
        __shared__ unsigned long long wmax[TPB / 64];
        __shared__ unsigned long long selk;
        unsigned long long prev = ~0ull;
        for (int r = 0; r < NMAX; ++r) {
            unsigned long long m = 0ull;
            #pragma unroll
            for (int k = 0; k < NMAX; ++k) {
                unsigned long long c = loc[k];
                m = (c < prev && c > m) ? c : m;
            }
            #pragma unroll
            for (int o = 32; o > 0; o >>= 1) {
                unsigned long long other = __shfl_down(m, o, 64);
                if (other > m) m = other;
            }
            if (lane == 0) wmax[wid] = m;
            __syncthreads();
            if (tid == 0) {
                unsigned long long mm = wmax[0];
                #pragma unroll
                for (int w = 1; w < TPB / 64; ++w) if (wmax[w] > mm) mm = wmax[w];
                selk = mm;
                keysOut[b * NMAX + r] = mm;
            }
            __syncthreads();
            prev = selk;
        }
    }
}

// ---------------- Kernel 2: finalize (merge + pdist std + combine) ------------
__global__ void __launch_bounds__(TPB)
finalize_kernel(const float* __restrict__ partials, int nPartials,
                const unsigned long long* __restrict__ keys,  // TOPK_BLOCKS*NMAX
                const float* __restrict__ R_xyz, int G,
                float* __restrict__ out, float invN) {
    __shared__ float red[TPB];
    __shared__ unsigned long long ck[TOPK_BLOCKS * NMAX];   // 320 keys
    __shared__ unsigned long long wmax[TPB / 64];
    __shared__ unsigned long long selk;
    __shared__ int   sel[NMAX];
    __shared__ float sxyz[NMAX][3];
    __shared__ float s_l1, s_sum;

    int tid = threadIdx.x, lane = tid & 63, wid = tid >> 6;

    // ---- Phase 1: reduce L1 partials (deterministic order) ----
    {
        float s = 0.f;
        for (int i = tid; i < nPartials; i += TPB) s += partials[i];
        red[tid] = s;
        __syncthreads();
        for (int off = TPB / 2; off > 0; off >>= 1) {
            if (tid < off) red[tid] += red[tid + off];
            __syncthreads();
        }
        if (tid == 0) s_l1 = red[0] * invN;
        __syncthreads();
    }

    // ---- Phase 2: merge the 16 block-top-20 lists -> global top-20 ----
    for (int i = tid; i < TOPK_BLOCKS * NMAX; i += TPB) ck[i] = keys[i];
    __syncthreads();
    {
        unsigned long long prev = ~0ull;
        for (int r = 0; r < NMAX; ++r) {
            unsigned long long m = 0ull;
            for (int i = tid; i < TOPK_BLOCKS * NMAX; i += TPB) {
                unsigned long long c = ck[i];
                m = (c < prev && c > m) ? c : m;
            }
            #pragma unroll
            for (int o = 32; o > 0; o >>= 1) {
                unsigned long long other = __shfl_down(m, o, 64);
                if (other > m) m = other;
            }
            if (lane == 0) wmax[wid] = m;
            __syncthreads();
            if (tid == 0) {
                unsigned long long mm = wmax[0];
                #pragma unroll
                for (int w = 1; w < TPB / 64; ++w) if (wmax[w] > mm) mm = wmax[w];
                selk = mm;
                sel[r] = (int)(~(unsigned)mm);
            }
            __syncthreads();
            prev = selk;
        }
    }

    // ---- Phase 3: gather xyz of selected points ----
    if (tid < NMAX * 3) {
        int i = tid / 3, d = tid % 3;
        sxyz[i][d] = R_xyz[d * G + sel[i]];
    }
    __syncthreads();

    // ---- Phase 4: 190 pairwise distances, std (ddof=1) ----
    float dval = 0.f;
    if (tid < NPAIR) {
        int k = tid, i = 0, rem = NMAX - 1;
        while (k >= rem) { k -= rem; ++i; --rem; }
        int j = i + 1 + k;
        float dx = sxyz[i][0] - sxyz[j][0];
        float dy = sxyz[i][1] - sxyz[j][1];
        float dz = sxyz[i][2] - sxyz[j][2];
        dval = sqrtf(dx * dx + dy * dy + dz * dz);
    }
    red[tid] = dval;
    __syncthreads();
    for (int off = TPB / 2; off > 0; off >>= 1) {
        if (tid < off) red[tid] += red[tid + off];
        __syncthreads();
    }
    if (tid == 0) s_sum = red[0];
    __syncthreads();
    red[tid] = dval * dval;
    __syncthreads();
    for (int off = TPB / 2; off > 0; off >>= 1) {
        if (tid < off) red[tid] += red[tid + off];
        __syncthreads();
    }
    if (tid == 0) {
        float sum   = s_sum;
        float sumsq = red[0];
        float mean  = sum / (float)NPAIR;
        float var   = (sumsq - (float)NPAIR * mean * mean) / (float)(NPAIR - 1);
        float stdv  = sqrtf(fmaxf(var, 0.f));
        float reg   = 0.01f * stdv;
        out[0] = s_l1 + reg;
        out[1] = s_l1;
        out[2] = reg;
    }
}

extern "C" void kernel_launch(void* const* d_in, const int* in_sizes, int n_in,
                              void* d_out, int out_size, void* d_ws, size_t ws_size,
                              hipStream_t stream) {
    const float* target = (const float*)d_in[0];
    const float* pred   = (const float*)d_in[1];
    const float* latent = (const float*)d_in[2];
    const float* R_xyz  = (const float*)d_in[3];
    float* out = (float*)d_out;

    int n    = in_sizes[0];          // 33,554,432
    int nLat = in_sizes[2];          // 64,800
    int G    = in_sizes[3] / 3;      // 64,800
    int nvec = n / 4;

    // ws layout: [0, 2048) floats = L1 partials; then 16*20 u64 keys.
    float* partials = (float*)d_ws;
    unsigned long long* keys = (unsigned long long*)((char*)d_ws + L1_BLOCKS * sizeof(float));

    fused_kernel<<<TOPK_BLOCKS + L1_BLOCKS, TPB, 0, stream>>>(
        (const float4*)target, (const float4*)pred, nvec,
        latent, nLat, partials, keys);

    finalize_kernel<<<1, TPB, 0, stream>>>(
        partials, L1_BLOCKS, keys, R_xyz, G, out, 1.0f / (float)n);
}